// Round 13
// baseline (1734.389 us; speedup 1.0000x reference)
//
#include <hip/hip_runtime.h>
#include <cstdint>
#include <cstddef>

#define B_ 64
#define T_ 512
#define I_ 256
#define H_ 1024
#define O_ 128

// Phase-B geometry (validated r9-r12): 8 groups (8 batch rows) x 8 slices
// (128 H-cols), 512-thread WGs, sc0 sc1 exchange, per-WG flags, wave0 poll,
// Phase A fused (r12). THIS ROUND (single variable): pipelined 3-deep poll
// (check spacing RT/3 instead of RT -> detect ~1.17RT vs ~1.5RT).
#define NGRP  8
#define NSLC  8
#define GROWS 8
#define SCOLS 128

typedef __attribute__((ext_vector_type(8))) short short8;   // 8 x bf16 frag
typedef __attribute__((ext_vector_type(4))) float f32x4;    // MFMA accumulator

__device__ __forceinline__ unsigned short f2bf(float f) {
    union { float f; unsigned int u; } v; v.f = f;
    unsigned int r = v.u + 0x7fffu + ((v.u >> 16) & 1u);   // RNE
    return (unsigned short)(r >> 16);
}
__device__ __forceinline__ float bf2f(unsigned short h) {
    union { float f; unsigned int u; } v; v.u = ((unsigned int)h) << 16;
    return v.f;
}
__device__ __forceinline__ short8 pack8(const float* p) {
    float4 a = *(const float4*)p;
    float4 b = *(const float4*)(p + 4);
    short8 r;
    r[0] = (short)f2bf(a.x); r[1] = (short)f2bf(a.y);
    r[2] = (short)f2bf(a.z); r[3] = (short)f2bf(a.w);
    r[4] = (short)f2bf(b.x); r[5] = (short)f2bf(b.y);
    r[6] = (short)f2bf(b.z); r[7] = (short)f2bf(b.w);
    return r;
}
__device__ __forceinline__ f32x4 zero4() {
    f32x4 v; v[0] = 0.f; v[1] = 0.f; v[2] = 0.f; v[3] = 0.f; return v;
}
__device__ __forceinline__ void vdrain() {
    asm volatile("s_waitcnt vmcnt(0)" ::: "memory");
}

// ---------------------------------------------------------------------------
// Phase B (+A fused): persistent recurrence, validated sc0 sc1 dataflow.
//   h_{t+1} = tanh( x[:,t,:]W_ih^T + b_ih + b_hh  +  h_t W_hh^T )
// Pipelined poll: 3 same-address coherent loads in flight; vmcnt(2) waits
// the OLDEST (in-order completion, m135). "+v" ties + sched_barrier order
// each check after its waitcnt (rule 18). A mis-ordered check can only
// read t-1 (stale reg) -> retry: degrades latency, never correctness.
// Flag store on wave1 (tid 64) keeps wave0's vmcnt poll-only. Leftover
// in-flight poll loads' regs kept alive past the stage vmcnt(0) (empty asm)
// so a landing load can't clobber a reallocated VGPR.
// ---------------------------------------------------------------------------
#define LDS_STRIDE 1032   // lds_h row stride (shorts); rows 16B-aligned
#define XSL 264           // lds_x row stride (shorts)
#define PO_S 20           // per-wave out tile stride (shorts)
#define POLL_BOUND 4096

__global__ __launch_bounds__(512, 1) void rnn_kernel(
        const float* __restrict__ W_hh, const float* __restrict__ W_ih,
        const float* __restrict__ b_ih, const float* __restrict__ b_hh,
        const float* __restrict__ x,
        unsigned short* __restrict__ hbuf, unsigned int* __restrict__ flags) {
    const int slice = blockIdx.x >> 3;   // 0..7 (128 H-cols each)
    const int group = blockIdx.x & 7;    // 0..7 (8 batch rows each)
    const int tid   = threadIdx.x;
    const int wave  = tid >> 6, lane = tid & 63;
    const int m     = lane & 15, quad = lane >> 4;
    const int col   = slice * SCOLS + wave * 16 + m;   // this lane's B column

    __shared__ unsigned short lds_h[GROWS * LDS_STRIDE];
    __shared__ unsigned short lds_po[8][GROWS * PO_S];
    __shared__ unsigned short lds_x2[2][GROWS * XSL];

    // Preload W_hh B-frags + W_ih B-frags + fused bias
    short8 bfrag[32];
    #pragma unroll
    for (int ks = 0; ks < 32; ++ks)
        bfrag[ks] = pack8(W_hh + (size_t)col * H_ + ks * 32 + quad * 8);
    short8 bfragIH[8];
    #pragma unroll
    for (int ks = 0; ks < 8; ++ks)
        bfragIH[ks] = pack8(W_ih + (size_t)col * I_ + ks * 32 + quad * 8);
    const float biasc = b_ih[col] + b_hh[col];

    unsigned int* gflags = flags + group * 8;       // 8 WG-flags per group
    unsigned int* myflag = gflags + slice;
    const unsigned int* pollp = gflags + (lane & 7);
    unsigned short* lds_po_w = &lds_po[wave][0];

    const int srow = tid >> 6, useg = tid & 63;       // staging role (8x64)
    const int prow = lane >> 3, pseg = lane & 7;      // publish role (8x8)

    // prologue: stage x[t=0] rows into lds_x2[0]
    {
        float4 v = *(const float4*)(
            x + ((size_t)(group * GROWS + srow) * T_ + 0) * I_ + useg * 4);
        uint2 p;
        p.x = (unsigned)f2bf(v.x) | ((unsigned)f2bf(v.y) << 16);
        p.y = (unsigned)f2bf(v.z) | ((unsigned)f2bf(v.w) << 16);
        *(uint2*)(&lds_x2[0][srow * XSL + useg * 4]) = p;
    }
    __syncthreads();

    for (int t = 0; t < T_; ++t) {
        const unsigned short* hsrc = hbuf + (size_t)(t & 1) * (B_ * H_)
                                          + (size_t)group * GROWS * H_;
        unsigned short* hdst = hbuf + (size_t)((t + 1) & 1) * (B_ * H_);

        unsigned pf0 = 0, pf1 = 0, pf2 = 0;   // poll pipeline regs

        // xp compute (independent of h): reads lds_x2[t&1] staged last step
        f32x4 axp = zero4();
        #pragma unroll
        for (int ks = 0; ks < 8; ++ks) {
            short8 a = *(const short8*)(
                &lds_x2[t & 1][(m & 7) * XSL + ks * 32 + quad * 8]);
            axp = __builtin_amdgcn_mfma_f32_16x16x32_bf16(
                a, bfragIH[ks], axp, 0, 0, 0);
        }

        // poll (WAVE 0 ONLY, pipelined 3-deep): all 8 WG-flags >= t
        if (t > 0) {
            if (wave == 0) {
                const unsigned target = (unsigned)t;
                int spins = 0;
                asm volatile("global_load_dword %0, %1, off sc0 sc1"
                             : "=v"(pf0) : "v"(pollp) : "memory");
                asm volatile("global_load_dword %0, %1, off sc0 sc1"
                             : "=v"(pf1) : "v"(pollp) : "memory");
                asm volatile("global_load_dword %0, %1, off sc0 sc1"
                             : "=v"(pf2) : "v"(pollp) : "memory");
                for (;;) {
                    asm volatile("s_waitcnt vmcnt(2)" : "+v"(pf0) :: "memory");
                    __builtin_amdgcn_sched_barrier(0);
                    if (__ballot(pf0 >= target) == ~0ull) break;
                    asm volatile("global_load_dword %0, %1, off sc0 sc1"
                                 : "=v"(pf0) : "v"(pollp) : "memory");
                    asm volatile("s_waitcnt vmcnt(2)" : "+v"(pf1) :: "memory");
                    __builtin_amdgcn_sched_barrier(0);
                    if (__ballot(pf1 >= target) == ~0ull) break;
                    asm volatile("global_load_dword %0, %1, off sc0 sc1"
                                 : "=v"(pf1) : "v"(pollp) : "memory");
                    asm volatile("s_waitcnt vmcnt(2)" : "+v"(pf2) :: "memory");
                    __builtin_amdgcn_sched_barrier(0);
                    if (__ballot(pf2 >= target) == ~0ull) break;
                    asm volatile("global_load_dword %0, %1, off sc0 sc1"
                                 : "=v"(pf2) : "v"(pollp) : "memory");
                    spins += 3;
                    if (spins >= POLL_BOUND) break;   // stall->absmax, no hang
                }
                // leftover loads stay in flight; regs kept alive below
            }
            __syncthreads();   // B_poll: release stage once flags observed
        }

        // cooperative stage: h (coherent, 16 KB) + x[t+1] (plain, 8 KB f32)
        {
            const unsigned short* rp = hsrc + (size_t)srow * H_;
            uint4 sv0, sv1;
            asm volatile("global_load_dwordx4 %0, %1, off sc0 sc1"
                         : "=v"(sv0) : "v"(rp + useg * 8) : "memory");
            asm volatile("global_load_dwordx4 %0, %1, off sc0 sc1"
                         : "=v"(sv1) : "v"(rp + (useg + 64) * 8) : "memory");
            if (t + 1 < T_) {
                float4 v = *(const float4*)(
                    x + ((size_t)(group * GROWS + srow) * T_ + (t + 1)) * I_
                      + useg * 4);
                uint2 p;
                p.x = (unsigned)f2bf(v.x) | ((unsigned)f2bf(v.y) << 16);
                p.y = (unsigned)f2bf(v.z) | ((unsigned)f2bf(v.w) << 16);
                *(uint2*)(&lds_x2[(t + 1) & 1][srow * XSL + useg * 4]) = p;
            }
            vdrain();   // also retires any leftover poll loads (wave0)
            asm volatile("" :: "v"(pf0), "v"(pf1), "v"(pf2));  // keep-alive
            *(uint4*)(&lds_h[srow * LDS_STRIDE + useg * 8]) = sv0;
            *(uint4*)(&lds_h[srow * LDS_STRIDE + (useg + 64) * 8]) = sv1;
        }
        __syncthreads();   // S_b: staged data visible to all waves

        // main K loop: A rows 8..15 duplicate 0..7 via (m&7)
        f32x4 acc[4];
        #pragma unroll
        for (int j = 0; j < 4; ++j) acc[j] = zero4();
        #pragma unroll
        for (int ks = 0; ks < 32; ks += 4) {
            #pragma unroll
            for (int j = 0; j < 4; ++j) {
                short8 a = *(const short8*)(
                    &lds_h[(m & 7) * LDS_STRIDE + (ks + j) * 32 + quad * 8]);
                acc[j] = __builtin_amdgcn_mfma_f32_16x16x32_bf16(
                    a, bfrag[ks + j], acc[j], 0, 0, 0);
            }
        }

        // epilogue: + xp(f32) + bias, tanh -> per-wave LDS transpose tile
        if (quad < 2) {
            #pragma unroll
            for (int r = 0; r < 4; ++r) {
                float v = acc[0][r] + acc[1][r] + acc[2][r] + acc[3][r]
                        + axp[r] + biasc;
                v = tanhf(v);
                lds_po_w[(quad * 4 + r) * PO_S + m] = f2bf(v);
            }
        }
        // wave-local readback + coherent publish + own-store drain
        {
            unsigned v = *(const unsigned*)(&lds_po_w[prow * PO_S + pseg * 2]);
            const void* p = hdst + (size_t)(group * GROWS + prow) * H_
                            + slice * SCOLS + wave * 16 + pseg * 2;
            asm volatile("global_store_dword %0, %1, off sc0 sc1"
                         :: "v"(p), "v"(v) : "memory");
            vdrain();
        }
        __syncthreads();   // S_a: whole WG drained + done reading lds_h/lds_x
        // per-WG flag on WAVE 1 (keeps wave0 vmcnt poll-only)
        if (tid == 64 && t < T_ - 1) {
            unsigned fv = (unsigned)(t + 1);
            asm volatile("global_store_dword %0, %1, off sc0 sc1"
                         :: "v"(myflag), "v"(fv) : "memory");
        }
    }
}

// ---------------------------------------------------------------------------
// Phase C: out[b][o] = h_final[b][:] . W_lin[o][:] + b_lin[o]; one wave/output
// ---------------------------------------------------------------------------
__global__ __launch_bounds__(256) void out_kernel(
        const unsigned short* __restrict__ hfinal, const float* __restrict__ W_lin,
        const float* __restrict__ b_lin, float* __restrict__ out) {
    const int gwave = (int)((blockIdx.x * 256 + threadIdx.x) >> 6);  // 0..8191
    const int lane  = threadIdx.x & 63;
    const int b = gwave >> 7, o = gwave & 127;

    const unsigned short* hp = hfinal + (size_t)b * H_ + lane * 16;
    const float*          wp = W_lin  + (size_t)o * H_ + lane * 16;
    float s = 0.f;
    #pragma unroll
    for (int j = 0; j < 16; ++j) s += bf2f(hp[j]) * wp[j];
    #pragma unroll
    for (int d = 32; d > 0; d >>= 1) s += __shfl_down(s, d, 64);
    if (lane == 0) out[(size_t)b * O_ + o] = s + b_lin[o];
}

// ---------------------------------------------------------------------------
extern "C" void kernel_launch(void* const* d_in, const int* in_sizes, int n_in,
                              void* d_out, int out_size, void* d_ws, size_t ws_size,
                              hipStream_t stream) {
    const float* x     = (const float*)d_in[0];
    const float* W_ih  = (const float*)d_in[1];
    const float* W_hh  = (const float*)d_in[2];
    const float* b_ih  = (const float*)d_in[3];
    const float* b_hh  = (const float*)d_in[4];
    const float* W_lin = (const float*)d_in[5];
    const float* b_lin = (const float*)d_in[6];

    unsigned short* hbuf  = (unsigned short*)d_ws;       // 2 x (64*1024) bf16
    unsigned int*   flags = (unsigned int*)(hbuf + 2 * (size_t)B_ * H_);

    // zero h ping-pong + flags
    (void)hipMemsetAsync(hbuf, 0,
                         2 * (size_t)B_ * H_ * sizeof(unsigned short)
                         + NGRP * 64 * sizeof(unsigned int), stream);

    rnn_kernel<<<64, 512, 0, stream>>>(W_hh, W_ih, b_ih, b_hh, x, hbuf, flags);
    out_kernel<<<(B_ * O_) / 4, 256, 0, stream>>>(hbuf, W_lin, b_lin, (float*)d_out);
}